// Round 2
// baseline (319.115 us; speedup 1.0000x reference)
//
#include <hip/hip_runtime.h>
#include <hip/hip_bf16.h>
#include <math.h>

#define BB 256
#define NN 256
#define DIN 128
#define NH 4
#define DH 32
#define HID 128   // NH*DH
#define NEG 0.2f
#define LN_EPS 1e-5f

typedef __hip_bfloat16 bf16;

__device__ __forceinline__ float b2f(bf16 v) { return __bfloat162float(v); }
__device__ __forceinline__ float lrelu(float x) { return fmaxf(x, NEG * x); }

// ---------------------------------------------------------------------------
// Kernel A: h1 = x @ W1 for 8 rows per block, plus per-head attention coeffs
//   asrc[b,h,n] = sum_d h[b,n,h,d]*att_src1[h,d]   (same for adst)
// 256 threads: c = t&127 (output column), half = t>>7 selects 4 rows.
// W1 staged once per block into LDS as bf16 (32 KB).
// h1 stored head-major: [B][H][N][DH] (bf16) so kernel B staging is contiguous.
// ---------------------------------------------------------------------------
__global__ __launch_bounds__(256) void k_gemm1(
    const float* __restrict__ x, const float* __restrict__ W1,
    const float* __restrict__ att_src1, const float* __restrict__ att_dst1,
    bf16* __restrict__ h1, float* __restrict__ asrc, float* __restrict__ adst)
{
    const int t = threadIdx.x;
    const int c = t & 127;               // output column 0..127
    const int half = t >> 7;             // 0..1 -> rows half*4 .. half*4+3
    const int row0 = blockIdx.x * 8;

    __shared__ bf16 W1s[DIN * HID];      // 32 KB
    __shared__ float xs[8 * DIN];        // 4 KB

    for (int idx = t; idx < DIN * HID; idx += 256)
        W1s[idx] = __float2bfloat16(W1[idx]);
    for (int idx = t; idx < 8 * DIN; idx += 256)
        xs[idx] = x[(size_t)row0 * DIN + idx];
    __syncthreads();

    float acc[4] = {0.f, 0.f, 0.f, 0.f};
    const float* xr = &xs[half * 4 * DIN];
#pragma unroll 4
    for (int k = 0; k < DIN; ++k) {
        const float w = b2f(W1s[k * HID + c]);
#pragma unroll
        for (int r = 0; r < 4; ++r)
            acc[r] = fmaf(xr[r * DIN + k], w, acc[r]);
    }

    const int hh = c >> 5, d = c & 31;
    const float asv = att_src1[c];       // (H,DH) flat == c
    const float adv = att_dst1[c];

#pragma unroll
    for (int r = 0; r < 4; ++r) {
        const int row = row0 + half * 4 + r;
        const int b = row >> 8, n = row & 255;
        h1[(((size_t)(b * NH + hh) * NN) + n) * DH + d] = __float2bfloat16(acc[r]);
        float vs = acc[r] * asv;
        float vd = acc[r] * adv;
#pragma unroll
        for (int m = 1; m < 32; m <<= 1) {
            vs += __shfl_xor(vs, m, 64);
            vd += __shfl_xor(vd, m, 64);
        }
        if (d == 0) {
            asrc[(b * NH + hh) * NN + n] = vs;
            adst[(b * NH + hh) * NN + n] = vd;
        }
    }
}

// ---------------------------------------------------------------------------
// Kernel B: layer-1 attention aggregation for one (b,head) per block.
//   out[i,d] = sum_j softmax_j(lrelu(dst_i + src_j)) * h[j,d]
// 256 threads, thread = destination row i. Two-pass softmax; h slice in LDS.
// LDS reads are wave-uniform (broadcast) -> conflict-free.
// Writes hagg as [B][N][HID] (bf16).
// ---------------------------------------------------------------------------
__global__ __launch_bounds__(256) void k_attn1(
    const bf16* __restrict__ h1, const float* __restrict__ asrc,
    const float* __restrict__ adst, bf16* __restrict__ hagg)
{
    const int bh = blockIdx.x;           // b*NH + hh
    const int i = threadIdx.x;
    __shared__ float hs[NN * DH];        // 32 KB
    __shared__ float ss[NN];

    const bf16* hp = h1 + (size_t)bh * NN * DH;
    for (int idx = i; idx < NN * DH; idx += 256)
        hs[idx] = b2f(hp[idx]);
    ss[i] = asrc[bh * NN + i];
    __syncthreads();

    const float di = adst[bh * NN + i];
    float m = -1e30f;
    for (int j = 0; j < NN; ++j)
        m = fmaxf(m, lrelu(di + ss[j]));

    float l = 0.f;
    float acc[DH];
#pragma unroll
    for (int d = 0; d < DH; ++d) acc[d] = 0.f;

    for (int j = 0; j < NN; ++j) {
        const float w = __expf(lrelu(di + ss[j]) - m);
        l += w;
        const float* hr = &hs[j * DH];
#pragma unroll
        for (int d = 0; d < DH; ++d) acc[d] = fmaf(w, hr[d], acc[d]);
    }
    const float inv = 1.f / l;
    const int b = bh >> 2, hh = bh & 3;
    bf16* op = hagg + ((size_t)(b * NN + i)) * HID + hh * DH;
#pragma unroll
    for (int d = 0; d < DH; ++d) op[d] = __float2bfloat16(acc[d] * inv);
}

// ---------------------------------------------------------------------------
// Kernel C: +b1, LayerNorm over HID=128, GEMV with W2 -> scalar h2 per node.
// 256 threads = 4 waves; one wave per row; each lane handles 2 dims.
// ---------------------------------------------------------------------------
__global__ __launch_bounds__(256) void k_ln(
    const bf16* __restrict__ hagg, const float* __restrict__ b1,
    const float* __restrict__ gamma, const float* __restrict__ beta,
    const float* __restrict__ W2, float* __restrict__ h2)
{
    const int wave = threadIdx.x >> 6, lane = threadIdx.x & 63;
    const int row = blockIdx.x * 4 + wave;
    const bf16* hp = hagg + (size_t)row * HID;
    const int d0 = lane * 2, d1 = d0 + 1;
    const float v0 = b2f(hp[d0]) + b1[d0];
    const float v1 = b2f(hp[d1]) + b1[d1];
    float s = v0 + v1, sq = v0 * v0 + v1 * v1;
#pragma unroll
    for (int m = 1; m < 64; m <<= 1) {
        s += __shfl_xor(s, m, 64);
        sq += __shfl_xor(sq, m, 64);
    }
    const float mu = s * (1.f / HID);
    const float var = sq * (1.f / HID) - mu * mu;
    const float rs = rsqrtf(var + LN_EPS);
    const float l0 = (v0 - mu) * rs * gamma[d0] + beta[d0];
    const float l1 = (v1 - mu) * rs * gamma[d1] + beta[d1];
    float p = l0 * W2[d0] + l1 * W2[d1];
#pragma unroll
    for (int m = 1; m < 64; m <<= 1) p += __shfl_xor(p, m, 64);
    if (lane == 0) h2[row] = p;
}

// ---------------------------------------------------------------------------
// Kernel D: layer-2 scalar attention (DOUT=1) + bias + ELU -> out fp32.
// One block per batch b; thread = destination row i.
// ---------------------------------------------------------------------------
__global__ __launch_bounds__(256) void k_attn2(
    const float* __restrict__ h2, const float* __restrict__ bias2,
    const float* __restrict__ att_src2, const float* __restrict__ att_dst2,
    float* __restrict__ out)
{
    const int b = blockIdx.x, i = threadIdx.x;
    __shared__ float hv[NN], sv[NN];
    const float s_att = att_src2[0], d_att = att_dst2[0];
    const float h = h2[b * NN + i];
    hv[i] = h;
    sv[i] = h * s_att;
    __syncthreads();

    const float di = h * d_att;
    float m = -1e30f;
    for (int j = 0; j < NN; ++j) m = fmaxf(m, lrelu(di + sv[j]));
    float l = 0.f, num = 0.f;
    for (int j = 0; j < NN; ++j) {
        const float w = __expf(lrelu(di + sv[j]) - m);
        l += w;
        num = fmaf(w, hv[j], num);
    }
    float o = num / l + bias2[0];
    o = (o > 0.f) ? o : (__expf(o) - 1.f);
    out[b * NN + i] = o;
}

extern "C" void kernel_launch(void* const* d_in, const int* in_sizes, int n_in,
                              void* d_out, int out_size, void* d_ws, size_t ws_size,
                              hipStream_t stream) {
    const float* x   = (const float*)d_in[0];
    // d_in[1] = adj (unused; graph fully connected)
    const float* W1  = (const float*)d_in[2];
    const float* b1  = (const float*)d_in[3];
    const float* as1 = (const float*)d_in[4];
    const float* ad1 = (const float*)d_in[5];
    const float* gam = (const float*)d_in[6];
    const float* bet = (const float*)d_in[7];
    const float* W2  = (const float*)d_in[8];
    const float* bi2 = (const float*)d_in[9];
    const float* as2 = (const float*)d_in[10];
    const float* ad2 = (const float*)d_in[11];
    float* out = (float*)d_out;

    char* ws = (char*)d_ws;
    size_t off = 0;
    bf16* h1    = (bf16*)(ws + off); off += (size_t)BB * NH * NN * DH * sizeof(bf16); // 16.8 MB
    float* asrc = (float*)(ws + off); off += (size_t)BB * NH * NN * sizeof(float);    // 1 MB
    float* adst = (float*)(ws + off); off += (size_t)BB * NH * NN * sizeof(float);    // 1 MB
    bf16* hagg  = (bf16*)(ws + off); off += (size_t)BB * NN * HID * sizeof(bf16);     // 16.8 MB
    float* h2   = (float*)(ws + off); off += (size_t)BB * NN * sizeof(float);         // 256 KB

    k_gemm1<<<BB * NN / 8, 256, 0, stream>>>(x, W1, as1, ad1, h1, asrc, adst);
    k_attn1<<<BB * NH, 256, 0, stream>>>(h1, asrc, adst, hagg);
    k_ln<<<BB * NN / 4, 256, 0, stream>>>(hagg, b1, gam, bet, W2, h2);
    k_attn2<<<BB, 256, 0, stream>>>(h2, bi2, as2, ad2, out);
}

// Round 3
// 200.635 us; speedup vs baseline: 1.5905x; 1.5905x over previous
//
#include <hip/hip_runtime.h>
#include <hip/hip_bf16.h>
#include <math.h>

#define BB 256
#define NN 256
#define DIN 128
#define NH 4
#define DH 32
#define HID 128   // NH*DH
#define NEG 0.2f
#define LN_EPS 1e-5f

typedef __hip_bfloat16 bf16;
typedef __attribute__((ext_vector_type(8))) short short8;
typedef __attribute__((ext_vector_type(4))) short short4v;
typedef __attribute__((ext_vector_type(4))) float float4v;

__device__ __forceinline__ float b2f(bf16 v) { return __bfloat162float(v); }
__device__ __forceinline__ short f2bs(float f) { return (short)__bfloat16_as_ushort(__float2bfloat16(f)); }
__device__ __forceinline__ float lrelu(float x) { return fmaxf(x, NEG * x); }

#define MFMA16(a, b, c) __builtin_amdgcn_mfma_f32_16x16x32_bf16(a, b, c, 0, 0, 0)

// ---------------------------------------------------------------------------
// Prep: W1T[n][k] = bf16(W1[k][n])  (128x128, 32 KB -> L1-resident B operand)
// ---------------------------------------------------------------------------
__global__ __launch_bounds__(256) void k_prep(const float* __restrict__ W1,
                                              short* __restrict__ W1T) {
    const int idx = blockIdx.x * 256 + threadIdx.x;  // 16384 total
    const int n = idx >> 7, k = idx & 127;
    W1T[idx] = f2bs(W1[k * HID + n]);
}

// ---------------------------------------------------------------------------
// GEMM1 (MFMA): h1 = x @ W1, 64 rows/block, full N=128, K=128.
// 4 waves; wave w owns rows [w*16, w*16+16), 8 n-tiles, 4 k-steps.
// Epilogue: C via padded LDS -> coalesced head-major h1 writes + asrc/adst.
// ---------------------------------------------------------------------------
__global__ __launch_bounds__(256) void k_gemm1(
    const float* __restrict__ x, const short* __restrict__ W1T,
    const float* __restrict__ att_src1, const float* __restrict__ att_dst1,
    bf16* __restrict__ h1, float* __restrict__ asrc, float* __restrict__ adst)
{
    const int t = threadIdx.x, wv = t >> 6, lane = t & 63;
    const int l16 = lane & 15, q = lane >> 4;
    const int row0 = blockIdx.x * 64;

    __shared__ float Cs[64 * 132];          // pad 128->132: conflict-light
    __shared__ float atts[HID], attd[HID];
    if (t < HID) { atts[t] = att_src1[t]; attd[t] = att_dst1[t]; }

    float4v acc[8];
#pragma unroll
    for (int i = 0; i < 8; ++i) acc[i] = (float4v){0.f, 0.f, 0.f, 0.f};

    const float* xrow = x + (size_t)(row0 + wv * 16 + l16) * DIN + q * 8;
#pragma unroll
    for (int ks = 0; ks < 4; ++ks) {
        const float4v xa = *(const float4v*)(xrow + ks * 32);
        const float4v xb = *(const float4v*)(xrow + ks * 32 + 4);
        short8 afr;
        afr[0] = f2bs(xa[0]); afr[1] = f2bs(xa[1]); afr[2] = f2bs(xa[2]); afr[3] = f2bs(xa[3]);
        afr[4] = f2bs(xb[0]); afr[5] = f2bs(xb[1]); afr[6] = f2bs(xb[2]); afr[7] = f2bs(xb[3]);
#pragma unroll
        for (int nt = 0; nt < 8; ++nt) {
            const short8 bfr = *(const short8*)(W1T + (nt * 16 + l16) * DIN + ks * 32 + q * 8);
            acc[nt] = MFMA16(afr, bfr, acc[nt]);
        }
    }

    // C/D layout: col = lane&15, row = (lane>>4)*4 + r
#pragma unroll
    for (int nt = 0; nt < 8; ++nt)
#pragma unroll
        for (int r = 0; r < 4; ++r)
            Cs[(wv * 16 + q * 4 + r) * 132 + nt * 16 + l16] = acc[nt][r];
    __syncthreads();

    // thread -> (head hh = t>>6, local row rl = t&63)
    const int hh = t >> 6, rl = t & 63;
    const int grow = row0 + rl, b = grow >> 8, n = grow & 255;
    float vs = 0.f, vd = 0.f;
    short hb[32] __attribute__((aligned(16)));
#pragma unroll
    for (int qq = 0; qq < 8; ++qq) {
        const float4v v = *(const float4v*)&Cs[rl * 132 + hh * 32 + qq * 4];
#pragma unroll
        for (int e = 0; e < 4; ++e) {
            const float f = v[e];
            const int d = qq * 4 + e;
            vs = fmaf(f, atts[hh * 32 + d], vs);
            vd = fmaf(f, attd[hh * 32 + d], vd);
            hb[d] = f2bs(f);
        }
    }
    short8* dst = (short8*)((short*)h1 + (((size_t)(b * NH + hh) * NN) + n) * DH);
#pragma unroll
    for (int qq = 0; qq < 4; ++qq) dst[qq] = *(short8*)&hb[qq * 8];
    asrc[(b * NH + hh) * NN + n] = vs;
    adst[(b * NH + hh) * NN + n] = vd;
}

// ---------------------------------------------------------------------------
// ATTN1 (MFMA): per (b,head) block, out^T = H^T[32x256] @ W^T[256x256].
// A-frags from LDS hT (transposed h, ds_read_b128); B-frags (softmax weights)
// generated in registers in B-layout. m_i = lrelu(d_i + smax) (lrelu monotone).
// Output head-major hagg[B][H][N][DH] bf16, normalized by l_i.
// ---------------------------------------------------------------------------
__global__ __launch_bounds__(256) void k_attn1(
    const bf16* __restrict__ h1, const float* __restrict__ asrc,
    const float* __restrict__ adst, bf16* __restrict__ hagg)
{
    const int bh = blockIdx.x, t = threadIdx.x, wv = t >> 6, lane = t & 63;
    const int l16 = lane & 15, q = lane >> 4;

    __shared__ short hT[DH * 264];   // [d][j], pitch 264 (pad 8): b128-friendly
    __shared__ float ss[NN], dd[NN];
    __shared__ float red[4];

    // stage: thread t = source row j; transpose into hT
    const short* hrow = (const short*)h1 + ((size_t)bh * NN + t) * DH;
    short rv[32] __attribute__((aligned(16)));
#pragma unroll
    for (int qq = 0; qq < 4; ++qq) *(short8*)&rv[qq * 8] = ((const short8*)hrow)[qq];
#pragma unroll
    for (int d = 0; d < DH; ++d) hT[d * 264 + t] = rv[d];

    const float sv = asrc[bh * NN + t];
    ss[t] = sv;
    dd[t] = adst[bh * NN + t];
    float mv = sv;
#pragma unroll
    for (int m = 32; m >= 1; m >>= 1) mv = fmaxf(mv, __shfl_xor(mv, m, 64));
    if (lane == 0) red[wv] = mv;
    __syncthreads();
    const float smax = fmaxf(fmaxf(red[0], red[1]), fmaxf(red[2], red[3]));

    // wave owns n-tiles wv*4 .. wv*4+3 (i dimension), both m-tiles (d dim)
    float dI[4], mI[4], lI[4];
#pragma unroll
    for (int u = 0; u < 4; ++u) {
        const int i = (wv * 4 + u) * 16 + l16;
        dI[u] = dd[i];
        mI[u] = lrelu(dI[u] + smax);
        lI[u] = 0.f;
    }
    float4v acc[4][2];
#pragma unroll
    for (int u = 0; u < 4; ++u) {
        acc[u][0] = (float4v){0.f, 0.f, 0.f, 0.f};
        acc[u][1] = (float4v){0.f, 0.f, 0.f, 0.f};
    }

#pragma unroll 2
    for (int ks = 0; ks < 8; ++ks) {
        const short8 a0 = *(const short8*)&hT[(l16) * 264 + ks * 32 + q * 8];
        const short8 a1 = *(const short8*)&hT[(16 + l16) * 264 + ks * 32 + q * 8];
        const float4v s0 = *(const float4v*)&ss[ks * 32 + q * 8];
        const float4v s1 = *(const float4v*)&ss[ks * 32 + q * 8 + 4];
        const float sj[8] = {s0[0], s0[1], s0[2], s0[3], s1[0], s1[1], s1[2], s1[3]};
#pragma unroll
        for (int u = 0; u < 4; ++u) {
            short8 bfr;
            float lsum = lI[u];
#pragma unroll
            for (int jj = 0; jj < 8; ++jj) {
                float e = dI[u] + sj[jj];
                e = fmaxf(e, NEG * e);
                const float w = __expf(e - mI[u]);
                lsum += w;
                bfr[jj] = f2bs(w);
            }
            lI[u] = lsum;
            acc[u][0] = MFMA16(a0, bfr, acc[u][0]);
            acc[u][1] = MFMA16(a1, bfr, acc[u][1]);
        }
    }

    // normalize + store (head-major): lane's i = nt*16+l16, 4 consecutive d
#pragma unroll
    for (int u = 0; u < 4; ++u) {
        float l = lI[u];
        l += __shfl_xor(l, 16, 64);
        l += __shfl_xor(l, 32, 64);
        const float inv = 1.f / l;
        const int i = (wv * 4 + u) * 16 + l16;
#pragma unroll
        for (int mt = 0; mt < 2; ++mt) {
            short4v o;
#pragma unroll
            for (int r = 0; r < 4; ++r) o[r] = f2bs(acc[u][mt][r] * inv);
            *(short4v*)((short*)hagg + ((size_t)bh * NN + i) * DH + mt * 16 + q * 4) = o;
        }
    }
}

// ---------------------------------------------------------------------------
// LN + W2 gemv: wave per row, 4 rows per wave (16 rows/block).
// hagg is head-major: d -> (hh = d>>5, dd = d&31).
// ---------------------------------------------------------------------------
__global__ __launch_bounds__(256) void k_ln(
    const bf16* __restrict__ hagg, const float* __restrict__ b1,
    const float* __restrict__ gamma, const float* __restrict__ beta,
    const float* __restrict__ W2, float* __restrict__ h2)
{
    const int wv = threadIdx.x >> 6, lane = threadIdx.x & 63;
#pragma unroll
    for (int it = 0; it < 4; ++it) {
        const int row = blockIdx.x * 16 + wv * 4 + it;
        const int b = row >> 8, n = row & 255;
        const int d0 = lane * 2, hh = d0 >> 5, dd0 = d0 & 31;
        const bf16* hp = hagg + (((size_t)(b * NH + hh) * NN) + n) * DH + dd0;
        const float v0 = b2f(hp[0]) + b1[d0];
        const float v1 = b2f(hp[1]) + b1[d0 + 1];
        float s = v0 + v1, sq = v0 * v0 + v1 * v1;
#pragma unroll
        for (int m = 1; m < 64; m <<= 1) {
            s += __shfl_xor(s, m, 64);
            sq += __shfl_xor(sq, m, 64);
        }
        const float mu = s * (1.f / HID);
        const float var = sq * (1.f / HID) - mu * mu;
        const float rs = rsqrtf(var + LN_EPS);
        const float l0 = (v0 - mu) * rs * gamma[d0] + beta[d0];
        const float l1 = (v1 - mu) * rs * gamma[d0 + 1] + beta[d0 + 1];
        float p = l0 * W2[d0] + l1 * W2[d0 + 1];
#pragma unroll
        for (int m = 1; m < 64; m <<= 1) p += __shfl_xor(p, m, 64);
        if (lane == 0) h2[row] = p;
    }
}

// ---------------------------------------------------------------------------
// Layer-2 scalar attention (DOUT=1) + bias + ELU.
// ---------------------------------------------------------------------------
__global__ __launch_bounds__(256) void k_attn2(
    const float* __restrict__ h2, const float* __restrict__ bias2,
    const float* __restrict__ att_src2, const float* __restrict__ att_dst2,
    float* __restrict__ out)
{
    const int b = blockIdx.x, i = threadIdx.x;
    __shared__ float hv[NN], sv[NN];
    const float s_att = att_src2[0], d_att = att_dst2[0];
    const float h = h2[b * NN + i];
    hv[i] = h;
    sv[i] = h * s_att;
    __syncthreads();

    const float di = h * d_att;
    float m = -1e30f;
    for (int j = 0; j < NN; ++j) m = fmaxf(m, lrelu(di + sv[j]));
    float l = 0.f, num = 0.f;
    for (int j = 0; j < NN; ++j) {
        const float w = __expf(lrelu(di + sv[j]) - m);
        l += w;
        num = fmaf(w, hv[j], num);
    }
    float o = num / l + bias2[0];
    o = (o > 0.f) ? o : (__expf(o) - 1.f);
    out[b * NN + i] = o;
}

extern "C" void kernel_launch(void* const* d_in, const int* in_sizes, int n_in,
                              void* d_out, int out_size, void* d_ws, size_t ws_size,
                              hipStream_t stream) {
    const float* x   = (const float*)d_in[0];
    const float* W1  = (const float*)d_in[2];
    const float* b1  = (const float*)d_in[3];
    const float* as1 = (const float*)d_in[4];
    const float* ad1 = (const float*)d_in[5];
    const float* gam = (const float*)d_in[6];
    const float* bet = (const float*)d_in[7];
    const float* W2  = (const float*)d_in[8];
    const float* bi2 = (const float*)d_in[9];
    const float* as2 = (const float*)d_in[10];
    const float* ad2 = (const float*)d_in[11];
    float* out = (float*)d_out;

    char* ws = (char*)d_ws;
    size_t off = 0;
    short* W1T  = (short*)(ws + off); off += (size_t)DIN * HID * sizeof(short);       // 32 KB
    bf16* h1    = (bf16*)(ws + off);  off += (size_t)BB * NH * NN * DH * sizeof(bf16); // 16.8 MB
    float* asrc = (float*)(ws + off); off += (size_t)BB * NH * NN * sizeof(float);     // 1 MB
    float* adst = (float*)(ws + off); off += (size_t)BB * NH * NN * sizeof(float);     // 1 MB
    bf16* hagg  = (bf16*)(ws + off);  off += (size_t)BB * NH * NN * DH * sizeof(bf16); // 16.8 MB
    float* h2   = (float*)(ws + off); off += (size_t)BB * NN * sizeof(float);          // 256 KB

    k_prep <<<DIN * HID / 256, 256, 0, stream>>>(W1, W1T);
    k_gemm1<<<BB * NN / 64, 256, 0, stream>>>(x, W1T, as1, ad1, h1, asrc, adst);
    k_attn1<<<BB * NH, 256, 0, stream>>>(h1, asrc, adst, hagg);
    k_ln   <<<BB * NN / 16, 256, 0, stream>>>(hagg, b1, gam, bet, W2, h2);
    k_attn2<<<BB, 256, 0, stream>>>(h2, bi2, as2, ad2, out);
}

// Round 4
// 163.718 us; speedup vs baseline: 1.9492x; 1.2255x over previous
//
#include <hip/hip_runtime.h>
#include <hip/hip_bf16.h>
#include <math.h>

#define BB 256
#define NN 256
#define DIN 128
#define NH 4
#define DH 32
#define HID 128   // NH*DH
#define NEG 0.2f
#define LN_EPS 1e-5f

typedef __hip_bfloat16 bf16;
typedef __attribute__((ext_vector_type(8))) short short8;
typedef __attribute__((ext_vector_type(4))) short short4v;
typedef __attribute__((ext_vector_type(4))) float float4v;

__device__ __forceinline__ float s2f(short s) {
    return __uint_as_float(((unsigned int)(unsigned short)s) << 16);
}
__device__ __forceinline__ short f2bs(float f) { return (short)__bfloat16_as_ushort(__float2bfloat16(f)); }
__device__ __forceinline__ float lrelu(float x) { return fmaxf(x, NEG * x); }

#define MFMA16(a, b, c) __builtin_amdgcn_mfma_f32_16x16x32_bf16(a, b, c, 0, 0, 0)

// ---------------------------------------------------------------------------
// Prep: W1T[n][k] = bf16(W1[k][n])  (128x128 shorts, L2-resident A operand)
// ---------------------------------------------------------------------------
__global__ __launch_bounds__(256) void k_prep(const float* __restrict__ W1,
                                              short* __restrict__ W1T) {
    const int idx = blockIdx.x * 256 + threadIdx.x;  // 16384
    const int n = idx >> 7, k = idx & 127;
    W1T[idx] = f2bs(W1[k * HID + n]);
}

// ---------------------------------------------------------------------------
// Mega-kernel: one block per batch element b (512 threads = 8 waves).
// Phase 0: stage x[b] -> LDS bf16 (pitch 136 shorts)
// Phase 1: hT[d][j] = W1T @ x^T via MFMA, written over the x region (pitch 272)
// Phase s: asrc/adst column sums; per-head smax; S1/S2 LN scalars
// Phase 2: per-head softmax-weight MFMA aggregation -> haggT[d][i] (pitch 268)
// Phase 3: LayerNorm folded into W2 dot -> h2[i] (split over 2 thread-halves)
// Phase 4: layer-2 scalar attention + bias + ELU -> out
// ---------------------------------------------------------------------------
__global__ __launch_bounds__(512) void k_mega(
    const float* __restrict__ x, const short* __restrict__ W1T,
    const float* __restrict__ as1, const float* __restrict__ ad1,
    const float* __restrict__ b1, const float* __restrict__ gamma,
    const float* __restrict__ beta, const float* __restrict__ W2,
    const float* __restrict__ bias2, const float* __restrict__ att_src2,
    const float* __restrict__ att_dst2, float* __restrict__ out)
{
    const int b = blockIdx.x, t = threadIdx.x;
    const int w = t >> 6, lane = t & 63;
    const int l16 = lane & 15, q = lane >> 4;

    __shared__ short uA[34816];          // 69632 B: xs[256][136] then hT[128][272]
    __shared__ short haggT[128 * 268];   // 68608 B
    __shared__ float ss[4][256], dd[4][256];   // 8 KB (dd reused as pp3, ss as pq)
    __shared__ float b1s[HID], gws[HID], bws[HID], atts[HID], attd[HID];
    __shared__ float smaxs[4], Ssc[2];
    __shared__ float h2v[NN], svv[NN];

    // ---- Phase 0: stage ----
    const float* xb = x + (size_t)b * NN * DIN;
#pragma unroll
    for (int it = 0; it < 16; ++it) {
        const int idx = t + it * 512;          // float4 index, 8192 total
        const int row = idx >> 5, c4 = idx & 31;
        const float4v v = ((const float4v*)xb)[idx];
        short4v p;
        p[0] = f2bs(v[0]); p[1] = f2bs(v[1]); p[2] = f2bs(v[2]); p[3] = f2bs(v[3]);
        *(short4v*)&uA[row * 136 + c4 * 4] = p;
    }
    if (t < HID) {
        b1s[t] = b1[t];
        const float w2v = W2[t];
        gws[t] = gamma[t] * w2v;
        bws[t] = beta[t] * w2v;
        atts[t] = as1[t];
        attd[t] = ad1[t];
    }
    __syncthreads();

    // ---- Phase 1: hT = W1T @ xs^T (wave w owns d-rows w*16..w*16+15) ----
    float4v acc1[16];
#pragma unroll
    for (int i = 0; i < 16; ++i) acc1[i] = (float4v){0.f, 0.f, 0.f, 0.f};
    const short* w1row = W1T + (w * 16 + l16) * DIN;
#pragma unroll
    for (int ks = 0; ks < 4; ++ks) {
        const short8 afr = *(const short8*)(w1row + ks * 32 + q * 8);
#pragma unroll
        for (int nt = 0; nt < 16; ++nt) {
            const short8 bfr = *(const short8*)&uA[(nt * 16 + l16) * 136 + ks * 32 + q * 8];
            acc1[nt] = MFMA16(afr, bfr, acc1[nt]);
        }
    }
    __syncthreads();   // all xs reads done; safe to overwrite region with hT

    // D layout: col(j) = l16, row(d offset) = q*4+r
#pragma unroll
    for (int nt = 0; nt < 16; ++nt)
#pragma unroll
        for (int r = 0; r < 4; ++r)
            uA[(w * 16 + q * 4 + r) * 272 + nt * 16 + l16] = f2bs(acc1[nt][r]);
    __syncthreads();

    // ---- asrc/adst column sums (from bf16 hT) ----
#pragma unroll
    for (int rep = 0; rep < 2; ++rep) {
        const int id = t + rep * 512;          // (hh, j), 1024 total
        const int hh = id >> 8, j = id & 255;
        float vs = 0.f, vd = 0.f;
#pragma unroll 8
        for (int d2 = 0; d2 < 32; ++d2) {
            const float hv = s2f(uA[(hh * 32 + d2) * 272 + j]);
            vs = fmaf(hv, atts[hh * 32 + d2], vs);
            vd = fmaf(hv, attd[hh * 32 + d2], vd);
        }
        ss[hh][j] = vs;
        dd[hh][j] = vd;
    }
    __syncthreads();

    // ---- per-head smax (waves 0-3); S1/S2 LN scalars (waves 4,5) ----
    if (w < 4) {
        float mv = fmaxf(fmaxf(ss[w][lane], ss[w][lane + 64]),
                         fmaxf(ss[w][lane + 128], ss[w][lane + 192]));
#pragma unroll
        for (int m = 1; m < 64; m <<= 1) mv = fmaxf(mv, __shfl_xor(mv, m, 64));
        if (lane == 0) smaxs[w] = mv;
    } else if (w == 4 || w == 5) {
        const float* src = (w == 4) ? gws : bws;
        float v = src[lane] + src[lane + 64];
#pragma unroll
        for (int m = 1; m < 64; m <<= 1) v += __shfl_xor(v, m, 64);
        if (lane == 0) Ssc[w - 4] = v;
    }
    __syncthreads();

    // ---- Phase 2: attention aggregation (wave w: head hh = w>>1, half = w&1) ----
    const int hh = w >> 1, half = w & 1;
    const float smax = smaxs[hh];
    float dI[8], mI[8], lI[8];
#pragma unroll
    for (int u = 0; u < 8; ++u) {
        const int i = half * 128 + u * 16 + l16;
        dI[u] = dd[hh][i];
        mI[u] = lrelu(dI[u] + smax);
        lI[u] = 0.f;
    }
    float4v acc2[8][2];
#pragma unroll
    for (int u = 0; u < 8; ++u) {
        acc2[u][0] = (float4v){0.f, 0.f, 0.f, 0.f};
        acc2[u][1] = (float4v){0.f, 0.f, 0.f, 0.f};
    }
    const short* hTh = &uA[(hh * 32) * 272];
#pragma unroll 2
    for (int ks = 0; ks < 8; ++ks) {
        const short8 a0 = *(const short8*)&hTh[l16 * 272 + ks * 32 + q * 8];
        const short8 a1 = *(const short8*)&hTh[(16 + l16) * 272 + ks * 32 + q * 8];
        const float4v s0 = *(const float4v*)&ss[hh][ks * 32 + q * 8];
        const float4v s1 = *(const float4v*)&ss[hh][ks * 32 + q * 8 + 4];
        const float sj[8] = {s0[0], s0[1], s0[2], s0[3], s1[0], s1[1], s1[2], s1[3]};
#pragma unroll
        for (int u = 0; u < 8; ++u) {
            short8 bfr;
            float ls = lI[u];
#pragma unroll
            for (int jj = 0; jj < 8; ++jj) {
                float e = dI[u] + sj[jj];
                e = fmaxf(e, NEG * e);
                const float wgt = __expf(e - mI[u]);
                ls += wgt;
                bfr[jj] = f2bs(wgt);
            }
            lI[u] = ls;
            acc2[u][0] = MFMA16(a0, bfr, acc2[u][0]);
            acc2[u][1] = MFMA16(a1, bfr, acc2[u][1]);
        }
    }
    // normalize + transposed store haggT[d][i]
#pragma unroll
    for (int u = 0; u < 8; ++u) {
        float l = lI[u];
        l += __shfl_xor(l, 16, 64);
        l += __shfl_xor(l, 32, 64);
        const float inv = 1.f / l;
        const int i = half * 128 + u * 16 + l16;
#pragma unroll
        for (int mt = 0; mt < 2; ++mt)
#pragma unroll
            for (int r = 0; r < 4; ++r)
                haggT[(hh * 32 + mt * 16 + q * 4 + r) * 268 + i] = f2bs(acc2[u][mt][r] * inv);
    }
    __syncthreads();

    // ---- Phase 3: LN + W2 dot (thread halves split the d range) ----
    float* pp3 = &dd[0][0];   // dd dead; reuse as partial buffer
    const int i3 = t & 255, hf = t >> 8;
    {
        float s = 0.f, sq = 0.f, t3 = 0.f;
#pragma unroll 8
        for (int dz = 0; dz < 64; ++dz) {
            const int d = hf * 64 + dz;
            const float v = s2f(haggT[d * 268 + i3]) + b1s[d];
            s += v;
            sq = fmaf(v, v, sq);
            t3 = fmaf(v, gws[d], t3);
        }
        if (hf) { pp3[i3 * 3] = s; pp3[i3 * 3 + 1] = sq; pp3[i3 * 3 + 2] = t3; }
        __syncthreads();
        if (!hf) {
            s += pp3[i3 * 3]; sq += pp3[i3 * 3 + 1]; t3 += pp3[i3 * 3 + 2];
            const float mu = s * (1.f / HID);
            const float var = sq * (1.f / HID) - mu * mu;
            const float rs = rsqrtf(var + LN_EPS);
            const float h2 = rs * (t3 - mu * Ssc[0]) + Ssc[1];
            h2v[i3] = h2;
            svv[i3] = h2 * att_src2[0];
        }
    }
    __syncthreads();

    // ---- Phase 4: layer-2 scalar attention + ELU (split over j halves) ----
    float* pq = &ss[0][0];    // ss dead; reuse
    const float d_att = att_dst2[0];
    const float di = h2v[i3] * d_att;
    float mloc = -1e30f;
#pragma unroll 4
    for (int jz = 0; jz < 128; ++jz)
        mloc = fmaxf(mloc, lrelu(di + svv[hf * 128 + jz]));
    if (hf) pp3[i3] = mloc;
    __syncthreads();
    if (!hf) pp3[i3] = fmaxf(mloc, pp3[i3]);
    __syncthreads();
    const float mfin = pp3[i3];
    float l2 = 0.f, num = 0.f;
#pragma unroll 4
    for (int jz = 0; jz < 128; ++jz) {
        const int j = hf * 128 + jz;
        const float wgt = __expf(lrelu(di + svv[j]) - mfin);
        l2 += wgt;
        num = fmaf(wgt, h2v[j], num);
    }
    if (hf) { pq[i3 * 2] = l2; pq[i3 * 2 + 1] = num; }
    __syncthreads();
    if (!hf) {
        l2 += pq[i3 * 2];
        num += pq[i3 * 2 + 1];
        float o = num / l2 + bias2[0];
        o = (o > 0.f) ? o : (__expf(o) - 1.f);
        out[b * NN + i3] = o;
    }
}

extern "C" void kernel_launch(void* const* d_in, const int* in_sizes, int n_in,
                              void* d_out, int out_size, void* d_ws, size_t ws_size,
                              hipStream_t stream) {
    const float* x   = (const float*)d_in[0];
    const float* W1  = (const float*)d_in[2];
    const float* b1  = (const float*)d_in[3];
    const float* as1 = (const float*)d_in[4];
    const float* ad1 = (const float*)d_in[5];
    const float* gam = (const float*)d_in[6];
    const float* bet = (const float*)d_in[7];
    const float* W2  = (const float*)d_in[8];
    const float* bi2 = (const float*)d_in[9];
    const float* as2 = (const float*)d_in[10];
    const float* ad2 = (const float*)d_in[11];
    float* out = (float*)d_out;

    short* W1T = (short*)d_ws;   // 32 KB

    k_prep<<<DIN * HID / 256, 256, 0, stream>>>(W1, W1T);
    k_mega<<<BB, 512, 0, stream>>>(x, W1T, as1, ad1, b1, gam, bet, W2,
                                   bi2, as2, ad2, out);
}

// Round 5
// 163.007 us; speedup vs baseline: 1.9577x; 1.0044x over previous
//
#include <hip/hip_runtime.h>
#include <hip/hip_bf16.h>
#include <math.h>

#define BB 256
#define NN 256
#define DIN 128
#define NH 4
#define DH 32
#define HID 128   // NH*DH
#define NEG 0.2f
#define LN_EPS 1e-5f

typedef __hip_bfloat16 bf16;
typedef __attribute__((ext_vector_type(8))) short short8;
typedef __attribute__((ext_vector_type(4))) float float4v;
typedef __attribute__((ext_vector_type(2))) unsigned int uint2v;

__device__ __forceinline__ float s2f(short s) {
    return __uint_as_float(((unsigned int)(unsigned short)s) << 16);
}
// round-half-up bf16 cast: 2 VALU ops, fine for positive/normal values
__device__ __forceinline__ short f2bs(float f) {
    return (short)((__float_as_uint(f) + 0x8000u) >> 16);
}
__device__ __forceinline__ unsigned int pack2(float a, float b) {
    return ((__float_as_uint(a) + 0x8000u) >> 16) |
           ((__float_as_uint(b) + 0x8000u) & 0xffff0000u);
}
__device__ __forceinline__ float lrelu(float x) { return fmaxf(x, NEG * x); }

#define MFMA16(a, b, c) __builtin_amdgcn_mfma_f32_16x16x32_bf16(a, b, c, 0, 0, 0)

// ---------------------------------------------------------------------------
// Mega-kernel: one block per batch element b. 1024 threads = 16 waves
// (4 waves/SIMD for latency hiding; grid == CU count so occupancy must come
// from block size). W1 transpose is done in-block (W1Ts lives in the haggT
// region, which is dead until phase-2 writes).
// ---------------------------------------------------------------------------
__global__ __launch_bounds__(1024) void k_mega(
    const float* __restrict__ x, const float* __restrict__ W1,
    const float* __restrict__ as1, const float* __restrict__ ad1,
    const float* __restrict__ b1, const float* __restrict__ gamma,
    const float* __restrict__ beta, const float* __restrict__ W2,
    const float* __restrict__ bias2, const float* __restrict__ att_src2,
    const float* __restrict__ att_dst2, float* __restrict__ out)
{
    const int b = blockIdx.x, t = threadIdx.x;
    const int w = t >> 6, lane = t & 63;
    const int l16 = lane & 15, q = lane >> 4;

    __shared__ short uA[34816];     // xs[256][136] -> hT[128][272] -> f32 scratch
    __shared__ short hR[34816];     // W1Ts[128][136] -> haggT[128][272]
    __shared__ float ss[NH][NN], dd[NH][NN];
    __shared__ float b1s[HID], gws[HID], bws[HID], atts[HID], attd[HID];
    __shared__ float smaxs[NH], Ssc[2];
    __shared__ float h2v[NN], svv[NN];

    // ---- Phase 0: stage x -> bf16 LDS; transpose W1 -> bf16 LDS; consts ----
    const float* xb = x + (size_t)b * NN * DIN;
#pragma unroll
    for (int it = 0; it < 8; ++it) {
        const int idx = t + it * 1024;           // 8192 float4s
        const int row = idx >> 5, c4 = idx & 31;
        const float4v v = ((const float4v*)xb)[idx];
        uint2v p;
        p[0] = pack2(v[0], v[1]);
        p[1] = pack2(v[2], v[3]);
        *(uint2v*)&uA[row * 136 + c4 * 4] = p;
    }
#pragma unroll
    for (int it = 0; it < 4; ++it) {
        const int idx = t + it * 1024;           // 4096 float4s of W1[k][n]
        const int k = idx >> 5, n4 = idx & 31;
        const float4v v = ((const float4v*)W1)[idx];
#pragma unroll
        for (int e = 0; e < 4; ++e)
            hR[(n4 * 4 + e) * 136 + k] = f2bs(v[e]);   // W1Ts[n][k]
    }
    if (t < HID) {
        b1s[t] = b1[t];
        const float w2v = W2[t];
        gws[t] = gamma[t] * w2v;
        bws[t] = beta[t] * w2v;
        atts[t] = as1[t];
        attd[t] = ad1[t];
    }
    __syncthreads();

    // ---- Phase 1: hT[d][j] = W1T @ x^T. wave w: dtile = w&7, jhalf = w>>3 ----
    const int dtile = w & 7, jhalf = w >> 3;
    float4v acc1[8];
#pragma unroll
    for (int i = 0; i < 8; ++i) acc1[i] = (float4v){0.f, 0.f, 0.f, 0.f};
    const short* arow = &hR[(dtile * 16 + l16) * 136];
#pragma unroll
    for (int ks = 0; ks < 4; ++ks) {
        const short8 afr = *(const short8*)&arow[ks * 32 + q * 8];
#pragma unroll
        for (int nt = 0; nt < 8; ++nt) {
            const short8 bfr = *(const short8*)&uA[((jhalf * 8 + nt) * 16 + l16) * 136 + ks * 32 + q * 8];
            acc1[nt] = MFMA16(afr, bfr, acc1[nt]);
        }
    }
    __syncthreads();   // xs + W1Ts fully consumed
#pragma unroll
    for (int nt = 0; nt < 8; ++nt)
#pragma unroll
        for (int r = 0; r < 4; ++r)
            uA[(dtile * 16 + q * 4 + r) * 272 + (jhalf * 8 + nt) * 16 + l16] = f2bs(acc1[nt][r]);
    __syncthreads();

    // ---- asrc/adst column sums: thread -> (hh = t>>8, j = t&255) ----
    {
        const int hs = t >> 8, js = t & 255;
        float vs = 0.f, vd = 0.f;
#pragma unroll 8
        for (int d2 = 0; d2 < 32; ++d2) {
            const float hv = s2f(uA[(hs * 32 + d2) * 272 + js]);
            vs = fmaf(hv, atts[hs * 32 + d2], vs);
            vd = fmaf(hv, attd[hs * 32 + d2], vd);
        }
        ss[hs][js] = vs;
        dd[hs][js] = vd;
    }
    __syncthreads();

    // ---- per-head smax (waves 0-3); LN scalars Sg=sum(gamma*W2), Sb=sum(beta*W2) ----
    if (w < 4) {
        float mv = fmaxf(fmaxf(ss[w][lane], ss[w][lane + 64]),
                         fmaxf(ss[w][lane + 128], ss[w][lane + 192]));
#pragma unroll
        for (int m = 1; m < 64; m <<= 1) mv = fmaxf(mv, __shfl_xor(mv, m, 64));
        if (lane == 0) smaxs[w] = mv;
    } else if (w == 4 || w == 5) {
        const float* src = (w == 4) ? gws : bws;
        float v = src[lane] + src[lane + 64];
#pragma unroll
        for (int m = 1; m < 64; m <<= 1) v += __shfl_xor(v, m, 64);
        if (lane == 0) Ssc[w - 4] = v;
    }
    __syncthreads();

    // ---- Phase 2: attention aggregation. wave w: head = w>>2, quarter = w&3 ----
    {
        const int hh = w >> 2, qtr = w & 3;
        const float smax = smaxs[hh];
        float dI[4], mI[4], lI[4];
#pragma unroll
        for (int u = 0; u < 4; ++u) {
            const int i = qtr * 64 + u * 16 + l16;
            dI[u] = dd[hh][i];
            mI[u] = lrelu(dI[u] + smax);
            lI[u] = 0.f;
        }
        float4v acc2[4][2];
#pragma unroll
        for (int u = 0; u < 4; ++u) {
            acc2[u][0] = (float4v){0.f, 0.f, 0.f, 0.f};
            acc2[u][1] = (float4v){0.f, 0.f, 0.f, 0.f};
        }
        const short* hTh = &uA[(hh * 32) * 272];
#pragma unroll 2
        for (int ks = 0; ks < 8; ++ks) {
            const short8 a0 = *(const short8*)&hTh[l16 * 272 + ks * 32 + q * 8];
            const short8 a1 = *(const short8*)&hTh[(16 + l16) * 272 + ks * 32 + q * 8];
            const float4v s0 = *(const float4v*)&ss[hh][ks * 32 + q * 8];
            const float4v s1 = *(const float4v*)&ss[hh][ks * 32 + q * 8 + 4];
            const float sj[8] = {s0[0], s0[1], s0[2], s0[3], s1[0], s1[1], s1[2], s1[3]};
#pragma unroll
            for (int u = 0; u < 4; ++u) {
                union { short8 s8; unsigned int u32[4]; } bfr;
                float ls = lI[u];
#pragma unroll
                for (int p = 0; p < 4; ++p) {
                    float e0 = dI[u] + sj[2 * p];
                    float e1 = dI[u] + sj[2 * p + 1];
                    e0 = fmaxf(e0, NEG * e0);
                    e1 = fmaxf(e1, NEG * e1);
                    const float w0 = __expf(e0 - mI[u]);
                    const float w1 = __expf(e1 - mI[u]);
                    ls += w0 + w1;
                    bfr.u32[p] = pack2(w0, w1);
                }
                lI[u] = ls;
                acc2[u][0] = MFMA16(a0, bfr.s8, acc2[u][0]);
                acc2[u][1] = MFMA16(a1, bfr.s8, acc2[u][1]);
            }
        }
        // normalize + transposed store haggT[d][i] (pitch 272) into hR
#pragma unroll
        for (int u = 0; u < 4; ++u) {
            float l = lI[u];
            l += __shfl_xor(l, 16, 64);
            l += __shfl_xor(l, 32, 64);
            const float inv = 1.f / l;
            const int i = qtr * 64 + u * 16 + l16;
#pragma unroll
            for (int mt = 0; mt < 2; ++mt)
#pragma unroll
                for (int r = 0; r < 4; ++r)
                    hR[(hh * 32 + mt * 16 + q * 4 + r) * 272 + i] = f2bs(acc2[u][mt][r] * inv);
        }
    }
    __syncthreads();

    // ---- Phase 3: LN folded into W2 dot. 4-way split over d ----
    float* pw = (float*)uA;   // hT dead; 17408 floats of scratch
    const int i3 = t & 255, hf = t >> 8;
    {
        float s = 0.f, sq = 0.f, t3 = 0.f;
#pragma unroll 8
        for (int dz = 0; dz < 32; ++dz) {
            const int d = hf * 32 + dz;
            const float v = s2f(hR[d * 272 + i3]) + b1s[d];
            s += v;
            sq = fmaf(v, v, sq);
            t3 = fmaf(v, gws[d], t3);
        }
        const int pbase = (hf * 256 + i3) * 3;
        pw[pbase] = s; pw[pbase + 1] = sq; pw[pbase + 2] = t3;
        __syncthreads();
        if (hf == 0) {
            for (int k = 1; k < 4; ++k) {
                const int pb = (k * 256 + i3) * 3;
                s += pw[pb]; sq += pw[pb + 1]; t3 += pw[pb + 2];
            }
            const float mu = s * (1.f / HID);
            const float var = sq * (1.f / HID) - mu * mu;
            const float rs = rsqrtf(var + LN_EPS);
            const float h2 = rs * (t3 - mu * Ssc[0]) + Ssc[1];
            h2v[i3] = h2;
            svv[i3] = h2 * att_src2[0];
        }
    }
    __syncthreads();

    // ---- Phase 4: layer-2 scalar attention + ELU. 4-way split over j ----
    {
        const float di = h2v[i3] * att_dst2[0];
        float mloc = -1e30f;
#pragma unroll 4
        for (int jz = 0; jz < 64; ++jz)
            mloc = fmaxf(mloc, lrelu(di + svv[hf * 64 + jz]));
        pw[4096 + hf * 256 + i3] = mloc;
        __syncthreads();
        float mfin = pw[4096 + i3];
#pragma unroll
        for (int k = 1; k < 4; ++k) mfin = fmaxf(mfin, pw[4096 + k * 256 + i3]);
        float l2 = 0.f, num = 0.f;
#pragma unroll 4
        for (int jz = 0; jz < 64; ++jz) {
            const int j = hf * 64 + jz;
            const float wgt = __expf(lrelu(di + svv[j]) - mfin);
            l2 += wgt;
            num = fmaf(wgt, h2v[j], num);
        }
        const int qb = 5120 + (hf * 256 + i3) * 2;
        pw[qb] = l2; pw[qb + 1] = num;
        __syncthreads();
        if (hf == 0) {
#pragma unroll
            for (int k = 1; k < 4; ++k) {
                const int pb = 5120 + (k * 256 + i3) * 2;
                l2 += pw[pb]; num += pw[pb + 1];
            }
            float o = num / l2 + bias2[0];
            o = (o > 0.f) ? o : (__expf(o) - 1.f);
            out[b * NN + i3] = o;
        }
    }
}

extern "C" void kernel_launch(void* const* d_in, const int* in_sizes, int n_in,
                              void* d_out, int out_size, void* d_ws, size_t ws_size,
                              hipStream_t stream) {
    const float* x   = (const float*)d_in[0];
    const float* W1  = (const float*)d_in[2];
    const float* b1  = (const float*)d_in[3];
    const float* as1 = (const float*)d_in[4];
    const float* ad1 = (const float*)d_in[5];
    const float* gam = (const float*)d_in[6];
    const float* bet = (const float*)d_in[7];
    const float* W2  = (const float*)d_in[8];
    const float* bi2 = (const float*)d_in[9];
    const float* as2 = (const float*)d_in[10];
    const float* ad2 = (const float*)d_in[11];
    float* out = (float*)d_out;

    k_mega<<<BB, 1024, 0, stream>>>(x, W1, as1, ad1, b1, gam, bet, W2,
                                    bi2, as2, ad2, out);
}

// Round 6
// 152.920 us; speedup vs baseline: 2.0868x; 1.0660x over previous
//
#include <hip/hip_runtime.h>
#include <hip/hip_bf16.h>
#include <math.h>

#define BB 256
#define NN 256
#define DIN 128
#define NH 4
#define DH 32
#define HID 128   // NH*DH
#define NEG 0.2f
#define LN_EPS 1e-5f
#define L2E 1.44269504f

typedef __hip_bfloat16 bf16;
typedef __attribute__((ext_vector_type(8))) short short8;
typedef __attribute__((ext_vector_type(4))) float float4v;
typedef __attribute__((ext_vector_type(2))) unsigned int uint2v;
typedef __attribute__((ext_vector_type(4))) unsigned int uint4v;

__device__ __forceinline__ float s2f(short s) {
    return __uint_as_float(((unsigned int)(unsigned short)s) << 16);
}
// round-half-up bf16 cast (2 ops)
__device__ __forceinline__ short f2bs(float f) {
    return (short)((__float_as_uint(f) + 0x8000u) >> 16);
}
// pack two floats -> two bf16 in one uint via v_perm_b32 (3 ops)
__device__ __forceinline__ unsigned int pack2(float a, float b) {
    return __builtin_amdgcn_perm(__float_as_uint(b) + 0x8000u,
                                 __float_as_uint(a) + 0x8000u, 0x07060302u);
}
__device__ __forceinline__ float lrelu(float x) { return fmaxf(x, NEG * x); }

#define MFMA16(a, b, c) __builtin_amdgcn_mfma_f32_16x16x32_bf16(a, b, c, 0, 0, 0)

// ---------------------------------------------------------------------------
// Mega-kernel: one block per batch element. 1024 threads = 16 waves.
// Softmax weights are SEPARABLE: w_ij = 2^lrelu(s'_j + d'_i)  (log2-domain)
//   = A_i*B_j   if s'_j >= -d'_i   (A=2^d', B=2^s')
//   = A'_i*B'_j otherwise          (A'=2^{.2d'}, B'=2^{.2s'})
// -> no per-weight exp; l_i comes from an extra MFMA with A=ones.
// ---------------------------------------------------------------------------
__global__ __launch_bounds__(1024) void k_mega(
    const float* __restrict__ x, const float* __restrict__ W1,
    const float* __restrict__ as1, const float* __restrict__ ad1,
    const float* __restrict__ b1, const float* __restrict__ gamma,
    const float* __restrict__ beta, const float* __restrict__ W2,
    const float* __restrict__ bias2, const float* __restrict__ att_src2,
    const float* __restrict__ att_dst2, float* __restrict__ out)
{
    const int b = blockIdx.x, t = threadIdx.x;
    const int w = t >> 6, lane = t & 63;
    const int l16 = lane & 15, q = lane >> 4;

    __shared__ short uA[34816];     // xs[256][136] -> hT[128][264] -> f32 scratch
    __shared__ short hR[34816];     // W1Ts[128][136] -> haggT[128][264]
    __shared__ float Bs[NH][NN], Bsp[NH][NN], dd[NH][NN];
    __shared__ float b1s[HID], gws[HID], bws[HID], atts[HID], attd[HID];
    __shared__ float Ssc[2];
    __shared__ float h2v[NN], svv[NN];

    // ---- Phase 0: stage x -> bf16 LDS; W1^T -> bf16 LDS (n-major, b128) ----
    const float* xb = x + (size_t)b * NN * DIN;
#pragma unroll
    for (int it = 0; it < 8; ++it) {
        const int idx = t + it * 1024;           // 8192 float4s
        const int row = idx >> 5, c4 = idx & 31;
        const float4v v = ((const float4v*)xb)[idx];
        uint2v p;
        p[0] = pack2(v[0], v[1]);
        p[1] = pack2(v[2], v[3]);
        *(uint2v*)&uA[row * 136 + c4 * 4] = p;
    }
    {   // W1Ts[n][k]: thread handles n = t&127, k in [kc*16, kc*16+16)
        const int n = t & 127, kc = t >> 7, k0 = kc * 16;
        float v[16];
#pragma unroll
        for (int e = 0; e < 16; ++e) v[e] = W1[(k0 + e) * HID + n];
        uint4v pa, pb;
#pragma unroll
        for (int e = 0; e < 4; ++e) {
            pa[e] = pack2(v[2 * e], v[2 * e + 1]);
            pb[e] = pack2(v[8 + 2 * e], v[9 + 2 * e]);
        }
        *(uint4v*)&hR[n * 136 + k0] = pa;
        *(uint4v*)&hR[n * 136 + k0 + 8] = pb;
    }
    if (t < HID) {
        b1s[t] = b1[t];
        const float w2v = W2[t];
        gws[t] = gamma[t] * w2v;
        bws[t] = beta[t] * w2v;
        atts[t] = as1[t] * L2E;     // log2e folded in
        attd[t] = ad1[t] * L2E;
    }
    __syncthreads();

    // ---- Phase 1: hT[d][j] = W1T @ x^T. wave w: dtile = w&7, jhalf = w>>3 ----
    const int dtile = w & 7, jhalf = w >> 3;
    float4v acc1[8];
#pragma unroll
    for (int i = 0; i < 8; ++i) acc1[i] = (float4v){0.f, 0.f, 0.f, 0.f};
    const short* arow = &hR[(dtile * 16 + l16) * 136];
#pragma unroll
    for (int ks = 0; ks < 4; ++ks) {
        const short8 afr = *(const short8*)&arow[ks * 32 + q * 8];
#pragma unroll
        for (int nt = 0; nt < 8; ++nt) {
            const short8 bfr = *(const short8*)&uA[((jhalf * 8 + nt) * 16 + l16) * 136 + ks * 32 + q * 8];
            acc1[nt] = MFMA16(afr, bfr, acc1[nt]);
        }
    }
    __syncthreads();   // xs + W1Ts fully consumed
#pragma unroll
    for (int nt = 0; nt < 8; ++nt)
#pragma unroll
        for (int r = 0; r < 4; ++r)
            uA[(dtile * 16 + q * 4 + r) * 264 + (jhalf * 8 + nt) * 16 + l16] = f2bs(acc1[nt][r]);
    __syncthreads();

    // ---- column sums (log2-scaled) + per-j exp tables ----
    {
        const int hs = t >> 8, js = t & 255;
        float vs = 0.f, vd = 0.f;
#pragma unroll 8
        for (int d2 = 0; d2 < 32; ++d2) {
            const float hv = s2f(uA[(hs * 32 + d2) * 264 + js]);
            vs = fmaf(hv, atts[hs * 32 + d2], vs);
            vd = fmaf(hv, attd[hs * 32 + d2], vd);
        }
        Bs[hs][js]  = exp2f(vs);
        Bsp[hs][js] = exp2f(NEG * vs);
        dd[hs][js]  = vd;
    }
    __syncthreads();

    // ---- Phase 2: attention aggregation. wave w: head = w>>2, quarter = w&3 ----
    {
        if (w < 2) {   // LN scalars on the side (consumed after next barrier)
            const float* src = (w == 0) ? gws : bws;
            float v = src[lane] + src[lane + 64];
#pragma unroll
            for (int m = 1; m < 64; m <<= 1) v += __shfl_xor(v, m, 64);
            if (lane == 0) Ssc[w] = v;
        }
        const int hh = w >> 2, qtr = w & 3;
        float Au[4], Apu[4], Tu[4];
#pragma unroll
        for (int u = 0; u < 4; ++u) {
            const float dv = dd[hh][qtr * 64 + u * 16 + l16];
            Au[u]  = exp2f(dv);
            Apu[u] = exp2f(NEG * dv);
            Tu[u]  = exp2f(-dv);
        }
        float4v acc2[4][2], accL[4];
#pragma unroll
        for (int u = 0; u < 4; ++u) {
            acc2[u][0] = (float4v){0.f, 0.f, 0.f, 0.f};
            acc2[u][1] = (float4v){0.f, 0.f, 0.f, 0.f};
            accL[u]    = (float4v){0.f, 0.f, 0.f, 0.f};
        }
        short8 ones;
#pragma unroll
        for (int e = 0; e < 8; ++e) ones[e] = (short)0x3F80;

        const short* hTh = &uA[(hh * 32) * 264];
#pragma unroll 2
        for (int ks = 0; ks < 8; ++ks) {
            const short8 a0 = *(const short8*)&hTh[l16 * 264 + ks * 32 + q * 8];
            const short8 a1 = *(const short8*)&hTh[(16 + l16) * 264 + ks * 32 + q * 8];
            const float4v bs0 = *(const float4v*)&Bs[hh][ks * 32 + q * 8];
            const float4v bs1 = *(const float4v*)&Bs[hh][ks * 32 + q * 8 + 4];
            const float4v bp0 = *(const float4v*)&Bsp[hh][ks * 32 + q * 8];
            const float4v bp1 = *(const float4v*)&Bsp[hh][ks * 32 + q * 8 + 4];
            const float bsj[8] = {bs0[0], bs0[1], bs0[2], bs0[3], bs1[0], bs1[1], bs1[2], bs1[3]};
            const float bpj[8] = {bp0[0], bp0[1], bp0[2], bp0[3], bp1[0], bp1[1], bp1[2], bp1[3]};
#pragma unroll
            for (int u = 0; u < 4; ++u) {
                union { short8 s8; unsigned int u32[4]; } bfr;
#pragma unroll
                for (int p = 0; p < 4; ++p) {
                    const bool c0 = bsj[2 * p]     >= Tu[u];
                    const bool c1 = bsj[2 * p + 1] >= Tu[u];
                    const float w0 = (c0 ? Au[u] : Apu[u]) * (c0 ? bsj[2 * p]     : bpj[2 * p]);
                    const float w1 = (c1 ? Au[u] : Apu[u]) * (c1 ? bsj[2 * p + 1] : bpj[2 * p + 1]);
                    bfr.u32[p] = pack2(w0, w1);
                }
                acc2[u][0] = MFMA16(a0, bfr.s8, acc2[u][0]);
                acc2[u][1] = MFMA16(a1, bfr.s8, acc2[u][1]);
                accL[u]    = MFMA16(ones, bfr.s8, accL[u]);
            }
        }
        // normalize + transposed store haggT[d][i] (pitch 264) into hR
#pragma unroll
        for (int u = 0; u < 4; ++u) {
            const float inv = 1.f / accL[u][0];
            const int i = qtr * 64 + u * 16 + l16;
#pragma unroll
            for (int mt = 0; mt < 2; ++mt)
#pragma unroll
                for (int r = 0; r < 4; ++r)
                    hR[(hh * 32 + mt * 16 + q * 4 + r) * 264 + i] = f2bs(acc2[u][mt][r] * inv);
        }
    }
    __syncthreads();

    // ---- Phase 3: LN folded into W2 dot. 4-way split over d ----
    float* pw = (float*)uA;   // hT dead; scratch
    const int i3 = t & 255, hf = t >> 8;
    {
        float s = 0.f, sq = 0.f, t3 = 0.f;
#pragma unroll 8
        for (int dz = 0; dz < 32; ++dz) {
            const int d = hf * 32 + dz;
            const float v = s2f(hR[d * 264 + i3]) + b1s[d];
            s += v;
            sq = fmaf(v, v, sq);
            t3 = fmaf(v, gws[d], t3);
        }
        const int pbase = (hf * 256 + i3) * 3;
        pw[pbase] = s; pw[pbase + 1] = sq; pw[pbase + 2] = t3;
        __syncthreads();
        if (hf == 0) {
            for (int k = 1; k < 4; ++k) {
                const int pb = (k * 256 + i3) * 3;
                s += pw[pb]; sq += pw[pb + 1]; t3 += pw[pb + 2];
            }
            const float mu = s * (1.f / HID);
            const float var = sq * (1.f / HID) - mu * mu;
            const float rs = rsqrtf(var + LN_EPS);
            const float h2 = rs * (t3 - mu * Ssc[0]) + Ssc[1];
            h2v[i3] = h2;
            svv[i3] = h2 * att_src2[0];
        }
    }
    __syncthreads();

    // ---- Phase 4: layer-2 scalar attention + ELU. 4-way split over j ----
    {
        const float di = h2v[i3] * att_dst2[0];
        float mloc = -1e30f;
#pragma unroll 4
        for (int jz = 0; jz < 64; ++jz)
            mloc = fmaxf(mloc, lrelu(di + svv[hf * 64 + jz]));
        pw[4096 + hf * 256 + i3] = mloc;
        __syncthreads();
        float mfin = pw[4096 + i3];
#pragma unroll
        for (int k = 1; k < 4; ++k) mfin = fmaxf(mfin, pw[4096 + k * 256 + i3]);
        float l2 = 0.f, num = 0.f;
#pragma unroll 4
        for (int jz = 0; jz < 64; ++jz) {
            const int j = hf * 64 + jz;
            const float wgt = __expf(lrelu(di + svv[j]) - mfin);
            l2 += wgt;
            num = fmaf(wgt, h2v[j], num);
        }
        const int qb = 5120 + (hf * 256 + i3) * 2;
        pw[qb] = l2; pw[qb + 1] = num;
        __syncthreads();
        if (hf == 0) {
#pragma unroll
            for (int k = 1; k < 4; ++k) {
                const int pb = 5120 + (k * 256 + i3) * 2;
                l2 += pw[pb]; num += pw[pb + 1];
            }
            float o = num / l2 + bias2[0];
            o = (o > 0.f) ? o : (__expf(o) - 1.f);
            out[b * NN + i3] = o;
        }
    }
}

extern "C" void kernel_launch(void* const* d_in, const int* in_sizes, int n_in,
                              void* d_out, int out_size, void* d_ws, size_t ws_size,
                              hipStream_t stream) {
    const float* x   = (const float*)d_in[0];
    const float* W1  = (const float*)d_in[2];
    const float* b1  = (const float*)d_in[3];
    const float* as1 = (const float*)d_in[4];
    const float* ad1 = (const float*)d_in[5];
    const float* gam = (const float*)d_in[6];
    const float* bet = (const float*)d_in[7];
    const float* W2  = (const float*)d_in[8];
    const float* bi2 = (const float*)d_in[9];
    const float* as2 = (const float*)d_in[10];
    const float* ad2 = (const float*)d_in[11];
    float* out = (float*)d_out;

    k_mega<<<BB, 1024, 0, stream>>>(x, W1, as1, ad1, b1, gam, bet, W2,
                                    bi2, as2, ad2, out);
}

// Round 7
// 146.420 us; speedup vs baseline: 2.1794x; 1.0444x over previous
//
#include <hip/hip_runtime.h>
#include <hip/hip_bf16.h>
#include <math.h>

#define BB 256
#define NN 256
#define DIN 128
#define NH 4
#define DH 32
#define HID 128   // NH*DH
#define NEG 0.2f
#define LN_EPS 1e-5f
#define L2E 1.44269504f

typedef __attribute__((ext_vector_type(8))) short short8;
typedef __attribute__((ext_vector_type(4))) float float4v;
typedef __attribute__((ext_vector_type(2))) unsigned int uint2v;
typedef __attribute__((ext_vector_type(4))) unsigned int uint4v;

// round-half-up bf16 cast (2 ops)
__device__ __forceinline__ short f2bs(float f) {
    return (short)((__float_as_uint(f) + 0x8000u) >> 16);
}
// pack two floats -> two bf16 in one uint (2 add + 1 perm)
__device__ __forceinline__ unsigned int pack2(float a, float b) {
    return __builtin_amdgcn_perm(__float_as_uint(b) + 0x8000u,
                                 __float_as_uint(a) + 0x8000u, 0x07060302u);
}

#define MFMA16(a, b, c) __builtin_amdgcn_mfma_f32_16x16x32_bf16(a, b, c, 0, 0, 0)

// ---------------------------------------------------------------------------
// One block per batch element, 1024 threads = 16 waves (4/SIMD).
// Key identities:
//   2^lrelu(z) = max(2^z, 2^{0.2 z})  -> branchless separable softmax weights
//   a_src = att.(W1^T x) = (att^T W1).x -> attention coeffs are extra GEMM rows
//   LN+W2 partials computed straight from phase-2 accumulator registers
// ---------------------------------------------------------------------------
__global__ __launch_bounds__(1024, 4) void k_mega(
    const float* __restrict__ x, const float* __restrict__ W1,
    const float* __restrict__ as1, const float* __restrict__ ad1,
    const float* __restrict__ b1, const float* __restrict__ gamma,
    const float* __restrict__ beta, const float* __restrict__ W2,
    const float* __restrict__ bias2, const float* __restrict__ att_src2,
    const float* __restrict__ att_dst2, float* __restrict__ out)
{
    const int b = blockIdx.x, t = threadIdx.x;
    const int w = t >> 6, lane = t & 63;
    const int l16 = lane & 15, q = lane >> 4;

    __shared__ short uA[34816];          // xs[256][136] -> hT[128][264]
    __shared__ short W1Ts[128 * 136];    // 34 KB, dead after phase 1
    __shared__ short awT[16 * 136];      // rows 0-3 src heads, 4-7 dst heads
    __shared__ float Bs[NH][NN], Bsp[NH][NN];
    __shared__ float ssraw[NH][NN], ddlog[NH][NN];
    __shared__ float b1s[HID], gws[HID], bws[HID];
    __shared__ float part[NH][NN * 3];   // phase-2 LN partials; reused phase 4
    __shared__ float Ssc[2];
    __shared__ float h2v[NN], Ej[NN], Epj[NN];

    // ---- Phase 0: stage x (bf16), W1^T (bf16), att-projected rows awT ----
    const float* xb = x + (size_t)b * NN * DIN;
#pragma unroll
    for (int it = 0; it < 8; ++it) {
        const int idx = t + it * 1024;           // 8192 float4s
        const int row = idx >> 5, c4 = idx & 31;
        const float4v v = ((const float4v*)xb)[idx];
        uint2v p;
        p[0] = pack2(v[0], v[1]);
        p[1] = pack2(v[2], v[3]);
        *(uint2v*)&uA[row * 136 + c4 * 4] = p;
    }
    {   // W1Ts[n][k]: thread handles n = t&127, k in [kc*16, kc*16+16)
        const int n = t & 127, kc = t >> 7, k0 = kc * 16;
        float v[16];
#pragma unroll
        for (int e = 0; e < 16; ++e) v[e] = W1[(k0 + e) * HID + n];
        uint4v pa, pb;
#pragma unroll
        for (int e = 0; e < 4; ++e) {
            pa[e] = pack2(v[2 * e], v[2 * e + 1]);
            pb[e] = pack2(v[8 + 2 * e], v[9 + 2 * e]);
        }
        *(uint4v*)&W1Ts[n * 136 + k0] = pa;
        *(uint4v*)&W1Ts[n * 136 + k0 + 8] = pb;
    }
    {   // awT[rr][k] = L2E * sum_d att[hh][d] * W1[k][hh*32+d]
        const int rr = t >> 7, k = t & 127;      // rr 0..7
        const int hh = rr & 3;
        const float* att = ((rr & 4) ? ad1 : as1) + hh * 32;
        const float* wrow = W1 + k * HID + hh * 32;
        float acc = 0.f;
#pragma unroll
        for (int e = 0; e < 8; ++e) {
            const float4v wv = *(const float4v*)(wrow + e * 4);
            const float4v av = *(const float4v*)(att + e * 4);
            acc += wv[0] * av[0] + wv[1] * av[1] + wv[2] * av[2] + wv[3] * av[3];
        }
        awT[rr * 136 + k] = f2bs(acc * L2E);
    }
    if (t < HID) {
        b1s[t] = b1[t];
        const float w2v = W2[t];
        gws[t] = gamma[t] * w2v;
        bws[t] = beta[t] * w2v;
    }
    __syncthreads();

    // ---- Phase 1: hT = W1T @ x^T (+ augmented att rows on waves 0/15) ----
    const int dtile = w & 7, jhalf = w >> 3;
    const bool isaug = (w == 0) || (w == 15);
    float4v acc1[8], accA[8];
#pragma unroll
    for (int i = 0; i < 8; ++i) {
        acc1[i] = (float4v){0.f, 0.f, 0.f, 0.f};
        accA[i] = (float4v){0.f, 0.f, 0.f, 0.f};
    }
    const short* arow = &W1Ts[(dtile * 16 + l16) * 136];
    const short* arow2 = &awT[l16 * 136];
#pragma unroll
    for (int ks = 0; ks < 4; ++ks) {
        const short8 afr = *(const short8*)&arow[ks * 32 + q * 8];
        short8 afr2;
        if (isaug) afr2 = *(const short8*)&arow2[ks * 32 + q * 8];
#pragma unroll
        for (int nt = 0; nt < 8; ++nt) {
            const short8 bfr = *(const short8*)&uA[((jhalf * 8 + nt) * 16 + l16) * 136 + ks * 32 + q * 8];
            acc1[nt] = MFMA16(afr, bfr, acc1[nt]);
            if (isaug) accA[nt] = MFMA16(afr2, bfr, accA[nt]);
        }
    }
    // raw attention coeffs (log2-scaled) from the augmented tile
    if (isaug && q < 2) {
        float (*dstA)[NN] = (q == 0) ? ssraw : ddlog;   // rows 0-3 src, 4-7 dst
#pragma unroll
        for (int nt = 0; nt < 8; ++nt)
#pragma unroll
            for (int r = 0; r < 4; ++r)
                dstA[r][jhalf * 128 + nt * 16 + l16] = accA[nt][r];
    }
    __syncthreads();   // xs + W1Ts consumed; ssraw/ddlog published
#pragma unroll
    for (int nt = 0; nt < 8; ++nt)
#pragma unroll
        for (int r = 0; r < 4; ++r)
            uA[(dtile * 16 + q * 4 + r) * 264 + (jhalf * 8 + nt) * 16 + l16] = f2bs(acc1[nt][r]);
    {   // per-j exp tables
        const int hs = t >> 8, js = t & 255;
        const float vs = ssraw[hs][js];
        Bs[hs][js] = exp2f(vs);
        Bsp[hs][js] = exp2f(NEG * vs);
    }
    __syncthreads();

    // ---- Phase 2: attention aggregation + in-register LN partials ----
    {
        if (w < 2) {   // LN scalars (consumed after next barrier)
            const float* src = (w == 0) ? gws : bws;
            float v = src[lane] + src[lane + 64];
#pragma unroll
            for (int m = 1; m < 64; m <<= 1) v += __shfl_xor(v, m, 64);
            if (lane == 0) Ssc[w] = v;
        }
        const int hh = w >> 2, qtr = w & 3;
        float Au[4], Apu[4];
#pragma unroll
        for (int u = 0; u < 4; ++u) {
            const float dv = ddlog[hh][qtr * 64 + u * 16 + l16];
            Au[u] = exp2f(dv);
            Apu[u] = exp2f(NEG * dv);
        }
        float4v acc2[4][2], accL[4];
#pragma unroll
        for (int u = 0; u < 4; ++u) {
            acc2[u][0] = (float4v){0.f, 0.f, 0.f, 0.f};
            acc2[u][1] = (float4v){0.f, 0.f, 0.f, 0.f};
            accL[u]    = (float4v){0.f, 0.f, 0.f, 0.f};
        }
        short8 ones;
#pragma unroll
        for (int e = 0; e < 8; ++e) ones[e] = (short)0x3F80;

        const short* hTh = &uA[(hh * 32) * 264];
#pragma unroll 2
        for (int ks = 0; ks < 8; ++ks) {
            const short8 a0 = *(const short8*)&hTh[l16 * 264 + ks * 32 + q * 8];
            const short8 a1 = *(const short8*)&hTh[(16 + l16) * 264 + ks * 32 + q * 8];
            const float4v bs0 = *(const float4v*)&Bs[hh][ks * 32 + q * 8];
            const float4v bs1 = *(const float4v*)&Bs[hh][ks * 32 + q * 8 + 4];
            const float4v bp0 = *(const float4v*)&Bsp[hh][ks * 32 + q * 8];
            const float4v bp1 = *(const float4v*)&Bsp[hh][ks * 32 + q * 8 + 4];
            const float bsj[8] = {bs0[0], bs0[1], bs0[2], bs0[3], bs1[0], bs1[1], bs1[2], bs1[3]};
            const float bpj[8] = {bp0[0], bp0[1], bp0[2], bp0[3], bp1[0], bp1[1], bp1[2], bp1[3]};
#pragma unroll
            for (int u = 0; u < 4; ++u) {
                union { short8 s8; unsigned int u32[4]; } bfr;
#pragma unroll
                for (int p = 0; p < 4; ++p) {
                    // w = 2^lrelu(s'+d') = max(2^{s'+d'}, 2^{0.2(s'+d')})
                    const float w0 = fmaxf(Au[u] * bsj[2 * p],     Apu[u] * bpj[2 * p]);
                    const float w1 = fmaxf(Au[u] * bsj[2 * p + 1], Apu[u] * bpj[2 * p + 1]);
                    bfr.u32[p] = pack2(w0, w1);
                }
                acc2[u][0] = MFMA16(a0, bfr.s8, acc2[u][0]);
                acc2[u][1] = MFMA16(a1, bfr.s8, acc2[u][1]);
                accL[u]    = MFMA16(ones, bfr.s8, accL[u]);
            }
        }
        // epilogue: normalize in registers, accumulate LN partials, reduce over q
        float b1r[8], gwr[8];
#pragma unroll
        for (int mt = 0; mt < 2; ++mt)
#pragma unroll
            for (int r = 0; r < 4; ++r) {
                const int d = hh * 32 + mt * 16 + q * 4 + r;
                b1r[mt * 4 + r] = b1s[d];
                gwr[mt * 4 + r] = gws[d];
            }
#pragma unroll
        for (int u = 0; u < 4; ++u) {
            const float inv = 1.f / accL[u][0];
            float s = 0.f, sq = 0.f, t3 = 0.f;
#pragma unroll
            for (int mt = 0; mt < 2; ++mt)
#pragma unroll
                for (int r = 0; r < 4; ++r) {
                    const float v = fmaf(acc2[u][mt][r], inv, b1r[mt * 4 + r]);
                    s += v;
                    sq = fmaf(v, v, sq);
                    t3 = fmaf(v, gwr[mt * 4 + r], t3);
                }
            s  += __shfl_xor(s, 16, 64);  s  += __shfl_xor(s, 32, 64);
            sq += __shfl_xor(sq, 16, 64); sq += __shfl_xor(sq, 32, 64);
            t3 += __shfl_xor(t3, 16, 64); t3 += __shfl_xor(t3, 32, 64);
            if (q == 0) {
                float* pp = &part[hh][(qtr * 64 + u * 16 + l16) * 3];
                pp[0] = s; pp[1] = sq; pp[2] = t3;
            }
        }
    }
    __syncthreads();

    // ---- Phase 3: finish LN + W2 dot; per-j layer-2 exp tables ----
    if (t < NN) {
        float s = 0.f, sq = 0.f, t3 = 0.f;
#pragma unroll
        for (int hh2 = 0; hh2 < 4; ++hh2) {
            const float* pp = &part[hh2][t * 3];
            s += pp[0]; sq += pp[1]; t3 += pp[2];
        }
        const float mu = s * (1.f / HID);
        const float var = sq * (1.f / HID) - mu * mu;
        const float rs = rsqrtf(var + LN_EPS);
        const float h2 = rs * (t3 - mu * Ssc[0]) + Ssc[1];
        h2v[t] = h2;
        const float e = h2 * att_src2[0];
        Ej[t]  = __expf(e);
        Epj[t] = __expf(NEG * e);
    }
    __syncthreads();

    // ---- Phase 4: layer-2 scalar attention + ELU (separable weights) ----
    {
        const int i3 = t & 255, hf = t >> 8;
        const float ed = h2v[i3] * att_dst2[0];
        const float Di = __expf(ed), Dip = __expf(NEG * ed);
        float l2 = 0.f, num = 0.f;
#pragma unroll 4
        for (int jz = 0; jz < 64; ++jz) {
            const int j = hf * 64 + jz;
            const float wgt = fmaxf(Di * Ej[j], Dip * Epj[j]);
            l2 += wgt;
            num = fmaf(wgt, h2v[j], num);
        }
        float* pw = &part[0][0];
        const int pb = (hf * 256 + i3) * 2;
        pw[pb] = l2; pw[pb + 1] = num;
        __syncthreads();
        if (hf == 0) {
#pragma unroll
            for (int k = 1; k < 4; ++k) {
                const int pk = (k * 256 + i3) * 2;
                l2 += pw[pk]; num += pw[pk + 1];
            }
            float o = num / l2 + bias2[0];
            o = (o > 0.f) ? o : (__expf(o) - 1.f);
            out[b * NN + i3] = o;
        }
    }
}

extern "C" void kernel_launch(void* const* d_in, const int* in_sizes, int n_in,
                              void* d_out, int out_size, void* d_ws, size_t ws_size,
                              hipStream_t stream) {
    const float* x   = (const float*)d_in[0];
    const float* W1  = (const float*)d_in[2];
    const float* b1  = (const float*)d_in[3];
    const float* as1 = (const float*)d_in[4];
    const float* ad1 = (const float*)d_in[5];
    const float* gam = (const float*)d_in[6];
    const float* bet = (const float*)d_in[7];
    const float* W2  = (const float*)d_in[8];
    const float* bi2 = (const float*)d_in[9];
    const float* as2 = (const float*)d_in[10];
    const float* ad2 = (const float*)d_in[11];
    float* out = (float*)d_out;

    k_mega<<<BB, 1024, 0, stream>>>(x, W1, as1, ad1, b1, gam, bet, W2,
                                    bi2, as2, ad2, out);
}